// Round 6
// baseline (5692.597 us; speedup 1.0000x reference)
//
#include <hip/hip_runtime.h>

// ObjectMsgEncoder on MI355X. f32 I/O, bf16 MFMA internally (f32 accumulate).
// R5 -> R6: k_mega __launch_bounds__(448) -> (448, 2). R4/R5 showed VGPR_Count
// pinned at 128 (compiler's 4-waves/EU heuristic) with ~4.5 KB/thread scratch
// spill traffic (3.6 GB WRITE_SIZE). (448,2) raises the cap to 256 VGPRs so
// Y[16] + pipelined B-fragments stay in registers. At offsets now 32-bit.

typedef __attribute__((ext_vector_type(8))) short short8;
typedef __attribute__((ext_vector_type(4))) float f32x4;

__device__ __forceinline__ float b2f(unsigned short u){
  union { unsigned int i; float f; } v; v.i = ((unsigned int)u) << 16; return v.f;
}
__device__ __forceinline__ unsigned short f2b(float f){
  union { float f; unsigned int i; } v; v.f = f;
  unsigned int i = v.i;
  unsigned int r = (i + 0x7FFFu + ((i >> 16) & 1u)) >> 16;
  return (unsigned short)r;
}
__device__ __forceinline__ float sigm(float x){ return 1.f/(1.f+__expf(-x)); }
__device__ __forceinline__ float tanh_f(float x){ float e = __expf(2.f*x); return 1.f - 2.f/(e+1.f); }

#define MFMA16(a,b,c) __builtin_amdgcn_mfma_f32_16x16x32_bf16((a),(b),(c),0,0,0)

// ---------------- K0: f32 -> bf16 weight conversion ----------------
__global__ __launch_bounds__(256) void k_cvt(const float* __restrict__ src,
                                             unsigned short* __restrict__ dst, int n){
  int i = blockIdx.x*256 + threadIdx.x;
  if (i < n) dst[i] = f2b(src[i]);
}

// ---------------- K1: olf0 = emb * mask (f32 -> bf16) ----------------
__global__ __launch_bounds__(256) void k_prep(const float* __restrict__ emb,
                                              const int* __restrict__ counts,
                                              unsigned short* __restrict__ olf){
  int bs = blockIdx.x;            // b*28+s
  int b = bs / 28; int s = bs - b*28;
  int e = threadIdx.x;
  olf[(size_t)bs*256 + e] = (s < counts[b]) ? f2b(emb[(size_t)bs*256 + e]) : (unsigned short)0;
}

// ---------------- K2a: zx = olf_l @ Wih^T  [7168,256]@[256,1024] -> bf16 ----------------
__global__ __launch_bounds__(256) void k_xgemm(const unsigned short* __restrict__ olf,
                                               const unsigned short* __restrict__ Wih,
                                               unsigned short* __restrict__ zx){
  const int tid = threadIdx.x;
  const int wid = tid >> 6, lane = tid & 63, col = lane & 15, quad = lane >> 4;
  const int m0 = blockIdx.x*64 + wid*16;
  short8 af[8];
  #pragma unroll
  for (int kt=0; kt<8; ++kt)
    af[kt] = *(const short8*)&olf[(size_t)(m0 + col)*256 + kt*32 + quad*8];
  #pragma unroll 4
  for (int nt=0; nt<64; ++nt){
    int n = nt*16 + col;
    f32x4 acc = (f32x4){0.f,0.f,0.f,0.f};
    #pragma unroll
    for (int kt=0; kt<8; ++kt){
      short8 bf = *(const short8*)&Wih[(size_t)n*256 + kt*32 + quad*8];
      acc = MFMA16(af[kt], bf, acc);
    }
    #pragma unroll
    for (int r=0; r<4; ++r)
      zx[(size_t)(m0 + quad*4 + r)*1024 + n] = f2b(acc[r]);
  }
}

// ---------------- K2b: LSTM recurrence, one layer: h@Whh^T + zx -> gates ----------------
__global__ __launch_bounds__(512) void k_rec(const unsigned short* __restrict__ zx,
                                             const unsigned short* __restrict__ Whh,
                                             const float* __restrict__ bih,
                                             const float* __restrict__ bhh,
                                             const int* __restrict__ counts,
                                             unsigned short* __restrict__ olf_out){
  __shared__ unsigned short Ab[16*264];   // [scene][unit 0..255], stride 264
  const int tid = threadIdx.x;
  const int wid = tid >> 6, lane = tid & 63, col = lane & 15, quad = lane >> 4;
  const int sc0 = blockIdx.x * 16;

  float bz[4][2];
  #pragma unroll
  for (int g=0; g<4; ++g){
    #pragma unroll
    for (int tt=0; tt<2; ++tt){
      int u = wid*32 + tt*16 + col;
      bz[g][tt] = bih[g*256+u] + bhh[g*256+u];
    }
  }
  int cnt4[4];
  #pragma unroll
  for (int r=0; r<4; ++r) cnt4[r] = counts[sc0 + quad*4 + r];

  float cst[2][4];
  #pragma unroll
  for (int tt=0; tt<2; ++tt){
    #pragma unroll
    for (int r=0; r<4; ++r) cst[tt][r] = 0.f;
  }
  for (int i=tid; i<16*264; i+=512) Ab[i] = 0;   // h0 = 0
  __syncthreads();

  for (int t=0; t<28; ++t){
    float zxv[4][2][4];
    #pragma unroll
    for (int g=0; g<4; ++g){
      #pragma unroll
      for (int tt=0; tt<2; ++tt){
        #pragma unroll
        for (int r=0; r<4; ++r)
          zxv[g][tt][r] = b2f(zx[((size_t)(sc0 + quad*4 + r)*28 + t)*1024
                                 + g*256 + wid*32 + tt*16 + col]);
      }
    }
    f32x4 acc[4][2];
    #pragma unroll
    for (int g=0; g<4; ++g){
      #pragma unroll
      for (int tt=0; tt<2; ++tt) acc[g][tt] = (f32x4){0.f,0.f,0.f,0.f};
    }
    #pragma unroll
    for (int kt=0; kt<8; ++kt){
      short8 a = *(const short8*)&Ab[col*264 + kt*32 + quad*8];
      #pragma unroll
      for (int g=0; g<4; ++g){
        #pragma unroll
        for (int tt=0; tt<2; ++tt){
          int n = g*256 + wid*32 + tt*16 + col;
          short8 bf = *(const short8*)&Whh[(size_t)n*256 + kt*32 + quad*8];
          acc[g][tt] = MFMA16(a, bf, acc[g][tt]);
        }
      }
    }
    __syncthreads();   // all reads of Ab(t) done
    #pragma unroll
    for (int tt=0; tt<2; ++tt){
      #pragma unroll
      for (int r=0; r<4; ++r){
        int s = quad*4 + r;
        int u = wid*32 + tt*16 + col;
        float zi = acc[0][tt][r] + zxv[0][tt][r] + bz[0][tt];
        float zf = acc[1][tt][r] + zxv[1][tt][r] + bz[1][tt];
        float zg = acc[2][tt][r] + zxv[2][tt][r] + bz[2][tt];
        float zo = acc[3][tt][r] + zxv[3][tt][r] + bz[3][tt];
        float cc = sigm(zf)*cst[tt][r] + sigm(zi)*tanh_f(zg);
        cst[tt][r] = cc;
        float hh = sigm(zo)*tanh_f(cc);
        unsigned short hb = f2b(hh);
        Ab[s*264 + u] = hb;                                   // raw h feeds recurrence
        olf_out[((size_t)(sc0+s)*28 + t)*256 + u] = (t < cnt4[r]) ? hb : (unsigned short)0;
      }
    }
    __syncthreads();
  }
}

// ---------------- K3: A-terms, [21504,256]@[256,512] -> bf16 ----------------
__global__ __launch_bounds__(256) void k_aterm(const unsigned short* __restrict__ olf,
                                               const unsigned short* __restrict__ Wgr,
                                               unsigned short* __restrict__ Aout){
  const int tid = threadIdx.x;
  const int wid = tid >> 6, lane = tid & 63, col = lane & 15, quad = lane >> 4;
  const int m0 = blockIdx.x*64 + wid*16;
  short8 af[8];
  #pragma unroll
  for (int kt=0; kt<8; ++kt)
    af[kt] = *(const short8*)&olf[(size_t)(m0 + col)*256 + kt*32 + quad*8];
  #pragma unroll 4
  for (int nt=0; nt<32; ++nt){
    int n = nt*16 + col;   // n<256: A_i (Wgr cols 0..255); else A_j (cols 256..511)
    const unsigned short* wb = (nt < 16) ? (Wgr + n*768) : (Wgr + (n-256)*768 + 256);
    f32x4 acc = (f32x4){0.f,0.f,0.f,0.f};
    #pragma unroll
    for (int kt=0; kt<8; ++kt){
      short8 bf = *(const short8*)&wb[kt*32 + quad*8];
      acc = MFMA16(af[kt], bf, acc);
    }
    #pragma unroll
    for (int r=0; r<4; ++r)
      Aout[(size_t)(m0 + quad*4 + r)*512 + nt*16 + col] = f2b(acc[r]);
  }
}

// ---------------- K4: fused per-(scene, j-tile) pipeline ----------------
// Static LDS: 112*264*2 + 112*4 + 1024*4 + 4*4 = 63,696 B
// (448,2): 256-VGPR cap, 2 waves/EU -> no accumulator spill (R5: 128-cap spilled
// ~4.5 KB/thread -> 3.6 GB WRITE_SIZE).
__global__ __launch_bounds__(448, 2) void k_mega(
    const float* __restrict__ centers, const int* __restrict__ counts,
    const float* __restrict__ Wr, const float* __restrict__ br,
    const unsigned short* __restrict__ Wgr, const float* __restrict__ bgr,
    const unsigned short* __restrict__ Wbc, const float* __restrict__ bbc,
    const float* __restrict__ alpha,
    const unsigned short* __restrict__ Wesa, const float* __restrict__ besa,
    const float* __restrict__ Wmu, const float* __restrict__ bmu,
    const unsigned short* __restrict__ Aterm, unsigned short* __restrict__ part){
  __shared__ unsigned short Xb[112*264];   // pair p = i*4+jc, 256 cols, stride 264
  __shared__ float gsb[112];
  __shared__ float lseB[1024];             // [jc*256+o]: max + ln(sum exp) over i
  __shared__ float lseG[4];                // per jc
  const int tid = threadIdx.x;
  const int wid = tid >> 6, lane = tid & 63, col = lane & 15, quad = lane >> 4;
  const int b = blockIdx.x / 7, jt = blockIdx.x - b*7;
  const int cb = counts[b];

  float av = alpha[0];
  float tv = sigm(av);
  float c1 = (1.f-tv)*(1.f-tv) + tv*tv;
  float c2 = 2.f*tv*(1.f-tv);

  int pis[4], pjs[4]; float pv[4];
  #pragma unroll
  for (int r=0; r<4; ++r){
    int p = wid*16 + quad*4 + r;        // local pair = C-row
    pis[r] = p >> 2;
    pjs[r] = jt*4 + (p & 3);
    pv[r] = (pis[r] < cb && pjs[r] < cb) ? 1.f : 0.f;
  }
  // S0: rlf0 = (mask_i*c_i - mask_j*c_j) @ Wr^T + br
  {
    int m = tid >> 2, sub = tid & 3;
    int i = m >> 2, j = jt*4 + (m & 3);
    float mi = (i < cb) ? 1.f : 0.f;
    float mj = (j < cb) ? 1.f : 0.f;
    const float* ci = centers + (b*28 + i)*3;
    const float* cj = centers + (b*28 + j)*3;
    float dx = mi*ci[0] - mj*cj[0];
    float dy = mi*ci[1] - mj*cj[1];
    float dz = mi*ci[2] - mj*cj[2];
    for (int e = sub*64; e < sub*64 + 64; ++e){
      float v = dx*Wr[e*3] + dy*Wr[e*3+1] + dz*Wr[e*3+2] + br[e];
      Xb[m*264 + e] = f2b(v);
    }
  }
  __syncthreads();

  const int arow = wid*16 + col;
  f32x4 Y[16];
  #pragma unroll 1
  for (int l=0; l<3; ++l){
    // GEMM1: Y = rlf @ Wgr_r^T
    #pragma unroll
    for (int nt=0; nt<16; ++nt) Y[nt] = (f32x4){0.f,0.f,0.f,0.f};
    #pragma unroll
    for (int kt=0; kt<8; ++kt){
      short8 a = *(const short8*)&Xb[arow*264 + kt*32 + quad*8];
      #pragma unroll
      for (int nt=0; nt<16; ++nt){
        int n = nt*16 + col;
        short8 bf = *(const short8*)&Wgr[n*768 + 512 + kt*32 + quad*8];
        Y[nt] = MFMA16(a, bf, Y[nt]);
      }
    }
    __syncthreads();
    // S2: rlf_lin = Y + A_i + A_j + bgr -> Xb (bf16). Y registers then free.
    int aib[4], ajb[4];
    #pragma unroll
    for (int r=0; r<4; ++r){
      aib[r] = (l*7168 + b*28 + pis[r])*512;
      ajb[r] = (l*7168 + b*28 + pjs[r])*512 + 256;
    }
    #pragma unroll
    for (int nt=0; nt<16; ++nt){
      int n = nt*16 + col;
      float bg = bgr[n];
      #pragma unroll
      for (int r=0; r<4; ++r){
        float v = Y[nt][r] + bg + b2f(Aterm[aib[r] + n]) + b2f(Aterm[ajb[r] + n]);
        Xb[(wid*16 + quad*4 + r)*264 + n] = f2b(v);
      }
    }
    __syncthreads();
    // GEMM2: Y = rlf_lin @ Wbc^T (reuses Y's registers)
    #pragma unroll
    for (int nt=0; nt<16; ++nt) Y[nt] = (f32x4){0.f,0.f,0.f,0.f};
    #pragma unroll
    for (int kt=0; kt<8; ++kt){
      short8 a = *(const short8*)&Xb[arow*264 + kt*32 + quad*8];
      #pragma unroll
      for (int nt=0; nt<16; ++nt){
        int n = nt*16 + col;
        short8 bf = *(const short8*)&Wbc[n*256 + kt*32 + quad*8];
        Y[nt] = MFMA16(a, bf, Y[nt]);
      }
    }
    __syncthreads();
    // S4: rlf = tanh(c1*rlf_lin + c2*(CP+bbc)) * rel_mask ; rlf_lin re-read from Xb
    #pragma unroll
    for (int nt=0; nt<16; ++nt){
      int n = nt*16 + col;
      float bb = bbc[n];
      #pragma unroll
      for (int r=0; r<4; ++r){
        int off = (wid*16 + quad*4 + r)*264 + n;
        float rl = b2f(Xb[off]);
        float bez = c1*rl + c2*(Y[nt][r] + bb);
        Xb[off] = f2b(tanh_f(bez) * pv[r]);
      }
    }
    __syncthreads();
  }
  // S5: resa = rlf @ Wesa^T + besa -> Xb bf16 + gscore from post-esa values
  #pragma unroll
  for (int nt=0; nt<16; ++nt) Y[nt] = (f32x4){0.f,0.f,0.f,0.f};
  #pragma unroll
  for (int kt=0; kt<8; ++kt){
    short8 a = *(const short8*)&Xb[arow*264 + kt*32 + quad*8];
    #pragma unroll
    for (int nt=0; nt<16; ++nt){
      int n = nt*16 + col;
      short8 bf = *(const short8*)&Wesa[n*256 + kt*32 + quad*8];
      Y[nt] = MFMA16(a, bf, Y[nt]);
    }
  }
  __syncthreads();   // all reads of rlf done before overwrite with resa
  float s4[4] = {0.f,0.f,0.f,0.f};
  #pragma unroll
  for (int nt=0; nt<16; ++nt){
    int n = nt*16 + col;
    float be = besa[n];
    float wmn = (Wmu[n] + Wmu[256+n] + Wmu[512+n]) * (1.f/3.f);
    #pragma unroll
    for (int r=0; r<4; ++r){
      float v = Y[nt][r] + be;
      Xb[(wid*16 + quad*4 + r)*264 + n] = f2b(v);
      s4[r] += v * wmn;
    }
  }
  #pragma unroll
  for (int r=0; r<4; ++r){
    s4[r] += __shfl_xor(s4[r], 1, 64);
    s4[r] += __shfl_xor(s4[r], 2, 64);
    s4[r] += __shfl_xor(s4[r], 4, 64);
    s4[r] += __shfl_xor(s4[r], 8, 64);
  }
  if (col == 0){
    float bm = (bmu[0] + bmu[1] + bmu[2]) * (1.f/3.f);
    #pragma unroll
    for (int r=0; r<4; ++r) gsb[wid*16 + quad*4 + r] = s4[r] + bm;
  }
  __syncthreads();
  // softmax stats over i (28 rows) per (jc,o) and per jc: lse = max + ln(sum exp)
  for (int it = tid; it < 1024; it += 448){
    int jc = it >> 8, o = it & 255;
    float mx = -1e30f;
    for (int i=0;i<28;++i) mx = fmaxf(mx, b2f(Xb[(i*4+jc)*264 + o]));
    float se = 0.f;
    for (int i=0;i<28;++i) se += __expf(b2f(Xb[(i*4+jc)*264 + o]) - mx);
    lseB[it] = mx + __logf(se);
  }
  if (tid < 4){
    int jc = tid;
    float mx = -1e30f;
    for (int i=0;i<28;++i) mx = fmaxf(mx, gsb[i*4+jc]);
    float se = 0.f;
    for (int i=0;i<28;++i) se += __expf(gsb[i*4+jc] - mx);
    lseG[jc] = mx + __logf(se);
  }
  __syncthreads();
  // partial output: sum over the block's 4 j's
  for (int it = tid; it < 7168; it += 448){
    int i = it >> 8, o = it & 255;
    float acc = 0.f;
    #pragma unroll
    for (int jc=0; jc<4; ++jc){
      int p = i*4 + jc;
      float v = b2f(Xb[p*264 + o]);
      float a = 0.5f*__expf(v - lseB[jc*256+o])
              + 0.5f*__expf(gsb[p] - lseG[jc]);
      acc += a * v;
    }
    part[((size_t)blockIdx.x*28 + i)*256 + o] = f2b(acc);
  }
}

// ---------------- K5: reduce 7 j-tiles, mask, write f32 ----------------
__global__ __launch_bounds__(256) void k_out(const unsigned short* __restrict__ part,
                                             const int* __restrict__ counts,
                                             float* __restrict__ out){
  int b = blockIdx.x / 28, i = blockIdx.x - b*28, o = threadIdx.x;
  float acc = 0.f;
  #pragma unroll
  for (int jt=0; jt<7; ++jt)
    acc += b2f(part[(((size_t)(b*7 + jt))*28 + i)*256 + o]);
  if (i >= counts[b]) acc = 0.f;
  out[(size_t)blockIdx.x*256 + o] = acc;
}

extern "C" void kernel_launch(void* const* d_in, const int* in_sizes, int n_in,
                              void* d_out, int out_size, void* d_ws, size_t ws_size,
                              hipStream_t stream){
  const float* centers = (const float*)d_in[0];
  const float* emb     = (const float*)d_in[1];
  const int*   counts  = (const int*)d_in[2];
  const float* Wr      = (const float*)d_in[3];
  const float* br      = (const float*)d_in[4];
  const float* Wih     = (const float*)d_in[5];
  const float* Whh     = (const float*)d_in[6];
  const float* bih     = (const float*)d_in[7];
  const float* bhh     = (const float*)d_in[8];
  const float* Wgr     = (const float*)d_in[9];
  const float* bgr     = (const float*)d_in[10];
  const float* Wbc     = (const float*)d_in[11];
  const float* bbc     = (const float*)d_in[12];
  const float* alpha   = (const float*)d_in[13];
  const float* Wesa    = (const float*)d_in[14];
  const float* besa    = (const float*)d_in[15];
  const float* Wmu     = (const float*)d_in[16];
  const float* bmu     = (const float*)d_in[17];
  // d_in[18], d_in[19] (Wlv, blv) are dead at eval time.

  // ws layout (60,424,192 bytes total):
  unsigned short* olf  = (unsigned short*)d_ws;                        // 3*7168*256 bf16 = 11,010,048 B
  unsigned short* At   = (unsigned short*)((char*)d_ws + 11010048);    // 3*7168*512 bf16 = 22,020,096 B
  unsigned short* zx   = At;                                           // 7168*1024 bf16 (aliases At; used before k_aterm)
  unsigned short* part = (unsigned short*)((char*)d_ws + 33030144);    // 1792*28*256 bf16 = 25,690,112 B
  unsigned short* wcv  = (unsigned short*)((char*)d_ws + 58720256);    // 851,968 bf16 = 1,703,936 B
  unsigned short* cWih  = wcv;            // 262144
  unsigned short* cWhh  = wcv + 262144;   // 262144
  unsigned short* cWgr  = wcv + 524288;   // 196608
  unsigned short* cWbc  = wcv + 720896;   // 65536
  unsigned short* cWesa = wcv + 786432;   // 65536
  float* outp = (float*)d_out;

  hipLaunchKernelGGL(k_cvt, dim3(1024), dim3(256), 0, stream, Wih,  cWih,  262144);
  hipLaunchKernelGGL(k_cvt, dim3(1024), dim3(256), 0, stream, Whh,  cWhh,  262144);
  hipLaunchKernelGGL(k_cvt, dim3(768),  dim3(256), 0, stream, Wgr,  cWgr,  196608);
  hipLaunchKernelGGL(k_cvt, dim3(256),  dim3(256), 0, stream, Wbc,  cWbc,  65536);
  hipLaunchKernelGGL(k_cvt, dim3(256),  dim3(256), 0, stream, Wesa, cWesa, 65536);

  hipLaunchKernelGGL(k_prep, dim3(7168), dim3(256), 0, stream, emb, counts, olf);
  // LSTM pass 1: olf0 -> olf1
  hipLaunchKernelGGL(k_xgemm, dim3(112), dim3(256), 0, stream, olf, cWih, zx);
  hipLaunchKernelGGL(k_rec,   dim3(16),  dim3(512), 0, stream, zx, cWhh, bih, bhh, counts,
                     olf + (size_t)7168*256);
  // LSTM pass 2: olf1 -> olf2
  hipLaunchKernelGGL(k_xgemm, dim3(112), dim3(256), 0, stream, olf + (size_t)7168*256, cWih, zx);
  hipLaunchKernelGGL(k_rec,   dim3(16),  dim3(512), 0, stream, zx, cWhh, bih, bhh, counts,
                     olf + (size_t)2*7168*256);
  hipLaunchKernelGGL(k_aterm, dim3(336), dim3(256), 0, stream, olf, cWgr, At);
  hipLaunchKernelGGL(k_mega,  dim3(1792), dim3(448), 0, stream,
                     centers, counts, Wr, br, cWgr, bgr, cWbc, bbc, alpha,
                     cWesa, besa, Wmu, bmu, At, part);
  hipLaunchKernelGGL(k_out,   dim3(7168), dim3(256), 0, stream, part, counts, outp);
}

// Round 7
// 2538.733 us; speedup vs baseline: 2.2423x; 2.2423x over previous
//
#include <hip/hip_runtime.h>

// ObjectMsgEncoder on MI355X. f32 I/O, bf16 MFMA internally (f32 accumulate).
// R6 -> R7: k_mega restructured to kill the persistent ~4.5 KB/thread scratch
// spill (R4-R6: WRITE_SIZE 3.6-3.8 GB regardless of launch_bounds):
//   * 896 threads / 14 waves; each wave = 16 pairs x 128 cols -> Y[8] (32 acc VGPRs)
//   * '#pragma unroll 1' on every MFMA kt-loop -> only 8 B-fragments in flight
//   * gscore via 8-threads-per-pair LDS reduction (no per-wave full-row s4)
// Live set ~100 VGPRs -> fits the 128 budget for 14 waves/CU without spill.

typedef __attribute__((ext_vector_type(8))) short short8;
typedef __attribute__((ext_vector_type(4))) float f32x4;

__device__ __forceinline__ float b2f(unsigned short u){
  union { unsigned int i; float f; } v; v.i = ((unsigned int)u) << 16; return v.f;
}
__device__ __forceinline__ unsigned short f2b(float f){
  union { float f; unsigned int i; } v; v.f = f;
  unsigned int i = v.i;
  unsigned int r = (i + 0x7FFFu + ((i >> 16) & 1u)) >> 16;
  return (unsigned short)r;
}
__device__ __forceinline__ float sigm(float x){ return 1.f/(1.f+__expf(-x)); }
__device__ __forceinline__ float tanh_f(float x){ float e = __expf(2.f*x); return 1.f - 2.f/(e+1.f); }

#define MFMA16(a,b,c) __builtin_amdgcn_mfma_f32_16x16x32_bf16((a),(b),(c),0,0,0)

// ---------------- K0: f32 -> bf16 weight conversion ----------------
__global__ __launch_bounds__(256) void k_cvt(const float* __restrict__ src,
                                             unsigned short* __restrict__ dst, int n){
  int i = blockIdx.x*256 + threadIdx.x;
  if (i < n) dst[i] = f2b(src[i]);
}

// ---------------- K1: olf0 = emb * mask (f32 -> bf16) ----------------
__global__ __launch_bounds__(256) void k_prep(const float* __restrict__ emb,
                                              const int* __restrict__ counts,
                                              unsigned short* __restrict__ olf){
  int bs = blockIdx.x;            // b*28+s
  int b = bs / 28; int s = bs - b*28;
  int e = threadIdx.x;
  olf[(size_t)bs*256 + e] = (s < counts[b]) ? f2b(emb[(size_t)bs*256 + e]) : (unsigned short)0;
}

// ---------------- K2a: zx = olf_l @ Wih^T  [7168,256]@[256,1024] -> bf16 ----------------
__global__ __launch_bounds__(256) void k_xgemm(const unsigned short* __restrict__ olf,
                                               const unsigned short* __restrict__ Wih,
                                               unsigned short* __restrict__ zx){
  const int tid = threadIdx.x;
  const int wid = tid >> 6, lane = tid & 63, col = lane & 15, quad = lane >> 4;
  const int m0 = blockIdx.x*64 + wid*16;
  short8 af[8];
  #pragma unroll
  for (int kt=0; kt<8; ++kt)
    af[kt] = *(const short8*)&olf[(size_t)(m0 + col)*256 + kt*32 + quad*8];
  #pragma unroll 4
  for (int nt=0; nt<64; ++nt){
    int n = nt*16 + col;
    f32x4 acc = (f32x4){0.f,0.f,0.f,0.f};
    #pragma unroll
    for (int kt=0; kt<8; ++kt){
      short8 bf = *(const short8*)&Wih[(size_t)n*256 + kt*32 + quad*8];
      acc = MFMA16(af[kt], bf, acc);
    }
    #pragma unroll
    for (int r=0; r<4; ++r)
      zx[(size_t)(m0 + quad*4 + r)*1024 + n] = f2b(acc[r]);
  }
}

// ---------------- K2b: LSTM recurrence, one layer: h@Whh^T + zx -> gates ----------------
__global__ __launch_bounds__(512) void k_rec(const unsigned short* __restrict__ zx,
                                             const unsigned short* __restrict__ Whh,
                                             const float* __restrict__ bih,
                                             const float* __restrict__ bhh,
                                             const int* __restrict__ counts,
                                             unsigned short* __restrict__ olf_out){
  __shared__ unsigned short Ab[16*264];   // [scene][unit 0..255], stride 264
  const int tid = threadIdx.x;
  const int wid = tid >> 6, lane = tid & 63, col = lane & 15, quad = lane >> 4;
  const int sc0 = blockIdx.x * 16;

  float bz[4][2];
  #pragma unroll
  for (int g=0; g<4; ++g){
    #pragma unroll
    for (int tt=0; tt<2; ++tt){
      int u = wid*32 + tt*16 + col;
      bz[g][tt] = bih[g*256+u] + bhh[g*256+u];
    }
  }
  int cnt4[4];
  #pragma unroll
  for (int r=0; r<4; ++r) cnt4[r] = counts[sc0 + quad*4 + r];

  float cst[2][4];
  #pragma unroll
  for (int tt=0; tt<2; ++tt){
    #pragma unroll
    for (int r=0; r<4; ++r) cst[tt][r] = 0.f;
  }
  for (int i=tid; i<16*264; i+=512) Ab[i] = 0;   // h0 = 0
  __syncthreads();

  for (int t=0; t<28; ++t){
    float zxv[4][2][4];
    #pragma unroll
    for (int g=0; g<4; ++g){
      #pragma unroll
      for (int tt=0; tt<2; ++tt){
        #pragma unroll
        for (int r=0; r<4; ++r)
          zxv[g][tt][r] = b2f(zx[((size_t)(sc0 + quad*4 + r)*28 + t)*1024
                                 + g*256 + wid*32 + tt*16 + col]);
      }
    }
    f32x4 acc[4][2];
    #pragma unroll
    for (int g=0; g<4; ++g){
      #pragma unroll
      for (int tt=0; tt<2; ++tt) acc[g][tt] = (f32x4){0.f,0.f,0.f,0.f};
    }
    #pragma unroll
    for (int kt=0; kt<8; ++kt){
      short8 a = *(const short8*)&Ab[col*264 + kt*32 + quad*8];
      #pragma unroll
      for (int g=0; g<4; ++g){
        #pragma unroll
        for (int tt=0; tt<2; ++tt){
          int n = g*256 + wid*32 + tt*16 + col;
          short8 bf = *(const short8*)&Whh[(size_t)n*256 + kt*32 + quad*8];
          acc[g][tt] = MFMA16(a, bf, acc[g][tt]);
        }
      }
    }
    __syncthreads();   // all reads of Ab(t) done
    #pragma unroll
    for (int tt=0; tt<2; ++tt){
      #pragma unroll
      for (int r=0; r<4; ++r){
        int s = quad*4 + r;
        int u = wid*32 + tt*16 + col;
        float zi = acc[0][tt][r] + zxv[0][tt][r] + bz[0][tt];
        float zf = acc[1][tt][r] + zxv[1][tt][r] + bz[1][tt];
        float zg = acc[2][tt][r] + zxv[2][tt][r] + bz[2][tt];
        float zo = acc[3][tt][r] + zxv[3][tt][r] + bz[3][tt];
        float cc = sigm(zf)*cst[tt][r] + sigm(zi)*tanh_f(zg);
        cst[tt][r] = cc;
        float hh = sigm(zo)*tanh_f(cc);
        unsigned short hb = f2b(hh);
        Ab[s*264 + u] = hb;                                   // raw h feeds recurrence
        olf_out[((size_t)(sc0+s)*28 + t)*256 + u] = (t < cnt4[r]) ? hb : (unsigned short)0;
      }
    }
    __syncthreads();
  }
}

// ---------------- K3: A-terms, [21504,256]@[256,512] -> bf16 ----------------
__global__ __launch_bounds__(256) void k_aterm(const unsigned short* __restrict__ olf,
                                               const unsigned short* __restrict__ Wgr,
                                               unsigned short* __restrict__ Aout){
  const int tid = threadIdx.x;
  const int wid = tid >> 6, lane = tid & 63, col = lane & 15, quad = lane >> 4;
  const int m0 = blockIdx.x*64 + wid*16;
  short8 af[8];
  #pragma unroll
  for (int kt=0; kt<8; ++kt)
    af[kt] = *(const short8*)&olf[(size_t)(m0 + col)*256 + kt*32 + quad*8];
  #pragma unroll 4
  for (int nt=0; nt<32; ++nt){
    int n = nt*16 + col;   // n<256: A_i (Wgr cols 0..255); else A_j (cols 256..511)
    const unsigned short* wb = (nt < 16) ? (Wgr + n*768) : (Wgr + (n-256)*768 + 256);
    f32x4 acc = (f32x4){0.f,0.f,0.f,0.f};
    #pragma unroll
    for (int kt=0; kt<8; ++kt){
      short8 bf = *(const short8*)&wb[kt*32 + quad*8];
      acc = MFMA16(af[kt], bf, acc);
    }
    #pragma unroll
    for (int r=0; r<4; ++r)
      Aout[(size_t)(m0 + quad*4 + r)*512 + nt*16 + col] = f2b(acc[r]);
  }
}

// ---------------- K4: fused per-(scene, j-tile) pipeline ----------------
// 896 thr / 14 waves: wave wv = (pair-group wid2 = wv>>1, col-half ch = wv&1).
// Each wave: 16 pairs x 128 cols, Y[8] acc. kt-loops unroll 1 (8 B-frags live).
// Static LDS: 112*264*2 + 112*4 + 1024*4 + 4*4 = 63,696 B
__global__ __launch_bounds__(896) void k_mega(
    const float* __restrict__ centers, const int* __restrict__ counts,
    const float* __restrict__ Wr, const float* __restrict__ br,
    const unsigned short* __restrict__ Wgr, const float* __restrict__ bgr,
    const unsigned short* __restrict__ Wbc, const float* __restrict__ bbc,
    const float* __restrict__ alpha,
    const unsigned short* __restrict__ Wesa, const float* __restrict__ besa,
    const float* __restrict__ Wmu, const float* __restrict__ bmu,
    const unsigned short* __restrict__ Aterm, unsigned short* __restrict__ part){
  __shared__ unsigned short Xb[112*264];   // pair p = i*4+jc, 256 cols, stride 264
  __shared__ float gsb[112];
  __shared__ float lseB[1024];             // [jc*256+o]: max + ln(sum exp) over i
  __shared__ float lseG[4];                // per jc
  const int tid = threadIdx.x;
  const int wv = tid >> 6;          // 0..13
  const int wid2 = wv >> 1;         // pair-group 0..6
  const int ch = wv & 1;            // column half 0/1
  const int lane = tid & 63, col = lane & 15, quad = lane >> 4;
  const int b = blockIdx.x / 7, jt = blockIdx.x - b*7;
  const int cb = counts[b];

  float av = alpha[0];
  float tv = sigm(av);
  float c1 = (1.f-tv)*(1.f-tv) + tv*tv;
  float c2 = 2.f*tv*(1.f-tv);

  int pis[4], pjs[4]; float pv[4];
  #pragma unroll
  for (int r=0; r<4; ++r){
    int p = wid2*16 + quad*4 + r;       // local pair = C-row
    pis[r] = p >> 2;
    pjs[r] = jt*4 + (p & 3);
    pv[r] = (pis[r] < cb && pjs[r] < cb) ? 1.f : 0.f;
  }
  // S0: rlf0 = (mask_i*c_i - mask_j*c_j) @ Wr^T + br  (8 threads per pair)
  {
    int m = tid >> 3, sub = tid & 7;
    int i = m >> 2, j = jt*4 + (m & 3);
    float mi = (i < cb) ? 1.f : 0.f;
    float mj = (j < cb) ? 1.f : 0.f;
    const float* ci = centers + (b*28 + i)*3;
    const float* cj = centers + (b*28 + j)*3;
    float dx = mi*ci[0] - mj*cj[0];
    float dy = mi*ci[1] - mj*cj[1];
    float dz = mi*ci[2] - mj*cj[2];
    for (int e = sub*32; e < sub*32 + 32; ++e){
      float v = dx*Wr[e*3] + dy*Wr[e*3+1] + dz*Wr[e*3+2] + br[e];
      Xb[m*264 + e] = f2b(v);
    }
  }
  __syncthreads();

  const int arow = wid2*16 + col;
  const int nbase = ch*128;
  f32x4 Y[8];
  #pragma unroll 1
  for (int l=0; l<3; ++l){
    // GEMM1: Y = rlf @ Wgr_r^T  (this wave's 128-col half)
    #pragma unroll
    for (int nt=0; nt<8; ++nt) Y[nt] = (f32x4){0.f,0.f,0.f,0.f};
    #pragma unroll 1
    for (int kt=0; kt<8; ++kt){
      short8 a = *(const short8*)&Xb[arow*264 + kt*32 + quad*8];
      #pragma unroll
      for (int nt=0; nt<8; ++nt){
        int n = nbase + nt*16 + col;
        short8 bf = *(const short8*)&Wgr[n*768 + 512 + kt*32 + quad*8];
        Y[nt] = MFMA16(a, bf, Y[nt]);
      }
    }
    __syncthreads();
    // S2: rlf_lin = Y + A_i + A_j + bgr -> Xb (bf16)
    int aib[4], ajb[4];
    #pragma unroll
    for (int r=0; r<4; ++r){
      aib[r] = (l*7168 + b*28 + pis[r])*512;
      ajb[r] = (l*7168 + b*28 + pjs[r])*512 + 256;
    }
    #pragma unroll
    for (int nt=0; nt<8; ++nt){
      int n = nbase + nt*16 + col;
      float bg = bgr[n];
      #pragma unroll
      for (int r=0; r<4; ++r){
        float v = Y[nt][r] + bg + b2f(Aterm[aib[r] + n]) + b2f(Aterm[ajb[r] + n]);
        Xb[(wid2*16 + quad*4 + r)*264 + n] = f2b(v);
      }
    }
    __syncthreads();
    // GEMM2: Y = rlf_lin @ Wbc^T
    #pragma unroll
    for (int nt=0; nt<8; ++nt) Y[nt] = (f32x4){0.f,0.f,0.f,0.f};
    #pragma unroll 1
    for (int kt=0; kt<8; ++kt){
      short8 a = *(const short8*)&Xb[arow*264 + kt*32 + quad*8];
      #pragma unroll
      for (int nt=0; nt<8; ++nt){
        int n = nbase + nt*16 + col;
        short8 bf = *(const short8*)&Wbc[n*256 + kt*32 + quad*8];
        Y[nt] = MFMA16(a, bf, Y[nt]);
      }
    }
    __syncthreads();
    // S4: rlf = tanh(c1*rlf_lin + c2*(CP+bbc)) * rel_mask ; rlf_lin re-read from Xb
    #pragma unroll
    for (int nt=0; nt<8; ++nt){
      int n = nbase + nt*16 + col;
      float bb = bbc[n];
      #pragma unroll
      for (int r=0; r<4; ++r){
        int off = (wid2*16 + quad*4 + r)*264 + n;
        float rl = b2f(Xb[off]);
        float bez = c1*rl + c2*(Y[nt][r] + bb);
        Xb[off] = f2b(tanh_f(bez) * pv[r]);
      }
    }
    __syncthreads();
  }
  // S5: resa = rlf @ Wesa^T + besa -> Xb (bf16)
  #pragma unroll
  for (int nt=0; nt<8; ++nt) Y[nt] = (f32x4){0.f,0.f,0.f,0.f};
  #pragma unroll 1
  for (int kt=0; kt<8; ++kt){
    short8 a = *(const short8*)&Xb[arow*264 + kt*32 + quad*8];
    #pragma unroll
    for (int nt=0; nt<8; ++nt){
      int n = nbase + nt*16 + col;
      short8 bf = *(const short8*)&Wesa[n*256 + kt*32 + quad*8];
      Y[nt] = MFMA16(a, bf, Y[nt]);
    }
  }
  __syncthreads();   // all reads of rlf done before overwrite with resa
  #pragma unroll
  for (int nt=0; nt<8; ++nt){
    int n = nbase + nt*16 + col;
    float be = besa[n];
    #pragma unroll
    for (int r=0; r<4; ++r)
      Xb[(wid2*16 + quad*4 + r)*264 + n] = f2b(Y[nt][r] + be);
  }
  __syncthreads();
  // gscore from post-esa Xb: 8 threads per pair
  {
    int m = tid >> 3, sub = tid & 7;
    float s = 0.f;
    for (int e = sub*32; e < sub*32 + 32; ++e){
      float wm = Wmu[e] + Wmu[256+e] + Wmu[512+e];
      s += b2f(Xb[m*264 + e]) * wm;
    }
    s += __shfl_xor(s, 1, 64);
    s += __shfl_xor(s, 2, 64);
    s += __shfl_xor(s, 4, 64);
    if (sub == 0)
      gsb[m] = s*(1.f/3.f) + (bmu[0] + bmu[1] + bmu[2])*(1.f/3.f);
  }
  __syncthreads();
  // softmax stats over i (28 rows) per (jc,o) and per jc: lse = max + ln(sum exp)
  for (int it = tid; it < 1024; it += 896){
    int jc = it >> 8, o = it & 255;
    float mx = -1e30f;
    for (int i=0;i<28;++i) mx = fmaxf(mx, b2f(Xb[(i*4+jc)*264 + o]));
    float se = 0.f;
    for (int i=0;i<28;++i) se += __expf(b2f(Xb[(i*4+jc)*264 + o]) - mx);
    lseB[it] = mx + __logf(se);
  }
  if (tid < 4){
    int jc = tid;
    float mx = -1e30f;
    for (int i=0;i<28;++i) mx = fmaxf(mx, gsb[i*4+jc]);
    float se = 0.f;
    for (int i=0;i<28;++i) se += __expf(gsb[i*4+jc] - mx);
    lseG[jc] = mx + __logf(se);
  }
  __syncthreads();
  // partial output: sum over the block's 4 j's
  for (int it = tid; it < 7168; it += 896){
    int i = it >> 8, o = it & 255;
    float acc = 0.f;
    #pragma unroll
    for (int jc=0; jc<4; ++jc){
      int p = i*4 + jc;
      float v = b2f(Xb[p*264 + o]);
      float a = 0.5f*__expf(v - lseB[jc*256+o])
              + 0.5f*__expf(gsb[p] - lseG[jc]);
      acc += a * v;
    }
    part[((size_t)blockIdx.x*28 + i)*256 + o] = f2b(acc);
  }
}

// ---------------- K5: reduce 7 j-tiles, mask, write f32 ----------------
__global__ __launch_bounds__(256) void k_out(const unsigned short* __restrict__ part,
                                             const int* __restrict__ counts,
                                             float* __restrict__ out){
  int b = blockIdx.x / 28, i = blockIdx.x - b*28, o = threadIdx.x;
  float acc = 0.f;
  #pragma unroll
  for (int jt=0; jt<7; ++jt)
    acc += b2f(part[(((size_t)(b*7 + jt))*28 + i)*256 + o]);
  if (i >= counts[b]) acc = 0.f;
  out[(size_t)blockIdx.x*256 + o] = acc;
}

extern "C" void kernel_launch(void* const* d_in, const int* in_sizes, int n_in,
                              void* d_out, int out_size, void* d_ws, size_t ws_size,
                              hipStream_t stream){
  const float* centers = (const float*)d_in[0];
  const float* emb     = (const float*)d_in[1];
  const int*   counts  = (const int*)d_in[2];
  const float* Wr      = (const float*)d_in[3];
  const float* br      = (const float*)d_in[4];
  const float* Wih     = (const float*)d_in[5];
  const float* Whh     = (const float*)d_in[6];
  const float* bih     = (const float*)d_in[7];
  const float* bhh     = (const float*)d_in[8];
  const float* Wgr     = (const float*)d_in[9];
  const float* bgr     = (const float*)d_in[10];
  const float* Wbc     = (const float*)d_in[11];
  const float* bbc     = (const float*)d_in[12];
  const float* alpha   = (const float*)d_in[13];
  const float* Wesa    = (const float*)d_in[14];
  const float* besa    = (const float*)d_in[15];
  const float* Wmu     = (const float*)d_in[16];
  const float* bmu     = (const float*)d_in[17];
  // d_in[18], d_in[19] (Wlv, blv) are dead at eval time.

  // ws layout (60,424,192 bytes total):
  unsigned short* olf  = (unsigned short*)d_ws;                        // 3*7168*256 bf16 = 11,010,048 B
  unsigned short* At   = (unsigned short*)((char*)d_ws + 11010048);    // 3*7168*512 bf16 = 22,020,096 B
  unsigned short* zx   = At;                                           // 7168*1024 bf16 (aliases At; used before k_aterm)
  unsigned short* part = (unsigned short*)((char*)d_ws + 33030144);    // 1792*28*256 bf16 = 25,690,112 B
  unsigned short* wcv  = (unsigned short*)((char*)d_ws + 58720256);    // 851,968 bf16 = 1,703,936 B
  unsigned short* cWih  = wcv;            // 262144
  unsigned short* cWhh  = wcv + 262144;   // 262144
  unsigned short* cWgr  = wcv + 524288;   // 196608
  unsigned short* cWbc  = wcv + 720896;   // 65536
  unsigned short* cWesa = wcv + 786432;   // 65536
  float* outp = (float*)d_out;

  hipLaunchKernelGGL(k_cvt, dim3(1024), dim3(256), 0, stream, Wih,  cWih,  262144);
  hipLaunchKernelGGL(k_cvt, dim3(1024), dim3(256), 0, stream, Whh,  cWhh,  262144);
  hipLaunchKernelGGL(k_cvt, dim3(768),  dim3(256), 0, stream, Wgr,  cWgr,  196608);
  hipLaunchKernelGGL(k_cvt, dim3(256),  dim3(256), 0, stream, Wbc,  cWbc,  65536);
  hipLaunchKernelGGL(k_cvt, dim3(256),  dim3(256), 0, stream, Wesa, cWesa, 65536);

  hipLaunchKernelGGL(k_prep, dim3(7168), dim3(256), 0, stream, emb, counts, olf);
  // LSTM pass 1: olf0 -> olf1
  hipLaunchKernelGGL(k_xgemm, dim3(112), dim3(256), 0, stream, olf, cWih, zx);
  hipLaunchKernelGGL(k_rec,   dim3(16),  dim3(512), 0, stream, zx, cWhh, bih, bhh, counts,
                     olf + (size_t)7168*256);
  // LSTM pass 2: olf1 -> olf2
  hipLaunchKernelGGL(k_xgemm, dim3(112), dim3(256), 0, stream, olf + (size_t)7168*256, cWih, zx);
  hipLaunchKernelGGL(k_rec,   dim3(16),  dim3(512), 0, stream, zx, cWhh, bih, bhh, counts,
                     olf + (size_t)2*7168*256);
  hipLaunchKernelGGL(k_aterm, dim3(336), dim3(256), 0, stream, olf, cWgr, At);
  hipLaunchKernelGGL(k_mega,  dim3(1792), dim3(896), 0, stream,
                     centers, counts, Wr, br, cWgr, bgr, cWbc, bbc, alpha,
                     cWesa, besa, Wmu, bmu, At, part);
  hipLaunchKernelGGL(k_out,   dim3(7168), dim3(256), 0, stream, part, counts, outp);
}